// Round 16
// baseline (622.424 us; speedup 1.0000x reference)
//
#include <hip/hip_runtime.h>
#include <hip/hip_bf16.h>
#include <stdint.h>

// Problem dims (fixed instance)
#define N_ROWS 6272      // B*H*W = 8*28*28, = 49*128 exactly
#define DIM    1024
#define M_ROWS 16384
#define KNN    9
#define BMS    128       // score tile M
#define BNS    128       // score tile N (= j-panel width)
#define NPANEL 128       // global 128-col panel count
#define TOPC   6         // candidates kept per (row, panel, col-half)
#define NCAND  (NPANEL * 2 * TOPC)   // 1536 per row
#define TRR    16        // rerank count
#define LSTR   160       // LDS row stride (bytes): 10*16B granules

typedef __attribute__((ext_vector_type(4))) float f32x4;
typedef __attribute__((ext_vector_type(4))) int   i32x4;
typedef __attribute__((ext_vector_type(16))) int  i32x16;

#define QSCALE 31.75f    // 127/4: clamp N(0,1) data to +-4, round to int8

__device__ __forceinline__ int quant8(float v) {
  return __float2int_rn(fminf(fmaxf(v, -4.f), 4.f) * QSCALE);
}

// ---- x transpose: 32x32 LDS tiles, coalesced read (hw) + write (c) ----
__global__ void k_prep_x(const float* __restrict__ feat,
                         float* __restrict__ xf, signed char* __restrict__ xq) {
  __shared__ float tile[32][33];
  const int ct = blockIdx.x & 31, nt = blockIdx.x >> 5;  // 32 c-tiles x 196 n-tiles
  const int c0 = ct * 32, n0 = nt * 32;
  const int tx = threadIdx.x & 31, ty = threadIdx.x >> 5; // ty in [0,8)
  {
    const int n = n0 + tx;
    const int b = n / 784, hw = n % 784;
    const float* src = feat + (size_t)b * 802816 + hw;
#pragma unroll
    for (int q = 0; q < 4; ++q)
      tile[ty + q * 8][tx] = src[(size_t)(c0 + ty + q * 8) * 784];
  }
  __syncthreads();
#pragma unroll
  for (int q = 0; q < 4; ++q) {
    const int nn = n0 + ty + q * 8;
    const int cc = c0 + tx;
    const float v = tile[tx][ty + q * 8];
    xf[(size_t)nn * DIM + cc] = v;
    xq[(size_t)nn * DIM + cc] = (signed char)quant8(v);
  }
}

// ---- memory bank: int8 copy + integer row squared norms (R10-proven) ----
__global__ void k_prep_m(const float* __restrict__ mb,
                         signed char* __restrict__ mq, int* __restrict__ mni) {
  const int j = blockIdx.x;
  const int t = threadIdx.x;
  const float* src = mb + (size_t)j * DIM;
  signed char* dst = mq + (size_t)j * DIM;
  int s = 0;
  for (int c = t; c < DIM; c += 256) {
    const int q = quant8(src[c]);
    dst[c] = (signed char)q;
    s += q * q;
  }
  __shared__ int red[4];
#pragma unroll
  for (int o = 32; o >= 1; o >>= 1) s += __shfl_down(s, o);
  if ((t & 63) == 0) red[t >> 6] = s;
  __syncthreads();
  if (t == 0) mni[j] = red[0] + red[1] + red[2] + red[3];
}

// ---- int8 MFMA distance GEMM: 40 KB LDS -> 4 blocks/CU TLP ----
// 1024 blocks = 8 XCD x 16 panels (2 MB i8 B resident/XCD) x 8 agroups.
// Single-buffer K-staging (sync, ds_write, sync, issue-next, MFMA);
// 2-stage epilogue: 128x64 swizzled Kbuf, top-6-of-32 scan + rank-count merge.
__launch_bounds__(256, 4)
__global__ void k_score(const signed char* __restrict__ xq,
                        const signed char* __restrict__ mq,
                        const int* __restrict__ mni,
                        unsigned int* __restrict__ cand) {
  __shared__ signed char S[40960];            // A @0 (20 KB) | B @20480 (20 KB)
  int* Kbuf = (int*)S;                        // 128 x 64 i32 = 32 KB (epilogue alias)
  unsigned* stage6 = (unsigned*)(S + 32768);  // 256 x 6 u32 = 6 KB (epilogue alias)

  const int bx = blockIdx.x;
  const int xcd = bx & 7, i = bx >> 3;        // dispatch round-robins XCDs
  const int panel = i & 15, agroup = i >> 4;  // 16 panels x 8 agroups per XCD
  const int j0 = xcd * 2048 + panel * BNS;
  const int pglob = xcd * 16 + panel;         // [0,128)

  const int t = threadIdx.x;
  const int lane = t & 63, w = t >> 6;
  const int wr = w >> 1, wc = w & 1;          // wave grid 2 x 2
  const int l31 = lane & 31, kh = lane >> 5;

  // staging chunk geometry: 4 x 16B per operand per K-tile per thread
  int srcOff[4], ldsOff[4];
#pragma unroll
  for (int cpy = 0; cpy < 4; ++cpy) {
    const int c = cpy * 256 + t;              // [0,1024)
    const int row = c >> 3, s = c & 7;
    srcOff[cpy] = row * DIM + s * 16;
    ldsOff[cpy] = row * LSTR + ((s ^ (row & 7)) << 4);
  }
  const signed char* bBase = mq + (size_t)j0 * DIM;

  int mn_[2];                                 // col-norms for this thread's cols
#pragma unroll
  for (int ni = 0; ni < 2; ++ni) mn_[ni] = mni[j0 + wc * 64 + ni * 32 + l31];

  const int tcount = (agroup == 0) ? 7 : 6;   // tiles = agroup + 8k < 49
#pragma unroll 1
  for (int k7 = 0; k7 < tcount; ++k7) {
    const int tile = agroup + 8 * k7;
    const int r0 = tile * BMS;
    const signed char* aBase = xq + (size_t)r0 * DIM;

    i32x16 acc[2][2];
#pragma unroll
    for (int mi = 0; mi < 2; ++mi)
#pragma unroll
      for (int ni = 0; ni < 2; ++ni)
#pragma unroll
        for (int r = 0; r < 16; ++r) acc[mi][ni][r] = 0;

    i32x4 ra[4], rb[4];
    // job prologue: issue K-tile 0 loads (overlaps previous job's epilogue)
#pragma unroll
    for (int cpy = 0; cpy < 4; ++cpy) {
      ra[cpy] = *(const i32x4*)(aBase + srcOff[cpy]);
      rb[cpy] = *(const i32x4*)(bBase + srcOff[cpy]);
    }

#pragma unroll 1
    for (int kt = 0; kt < 8; ++kt) {
      __syncthreads();                        // S free; drains ra/rb loads
#pragma unroll
      for (int cpy = 0; cpy < 4; ++cpy) {
        *(i32x4*)(S + ldsOff[cpy]) = ra[cpy];
        *(i32x4*)(S + 20480 + ldsOff[cpy]) = rb[cpy];
      }
      __syncthreads();                        // tile kt resident for ALL waves
      if (kt < 7) {                           // issue next-tile loads early
        const int kk = (kt + 1) * 128;
#pragma unroll
        for (int cpy = 0; cpy < 4; ++cpy) {
          ra[cpy] = *(const i32x4*)(aBase + srcOff[cpy] + kk);
          rb[cpy] = *(const i32x4*)(bBase + srcOff[cpy] + kk);
        }
      }
      __builtin_amdgcn_s_setprio(1);
#pragma unroll
      for (int ks = 0; ks < 4; ++ks) {
        const int sr = 2 * ks + kh;
        i32x4 a[2], b[2];
#pragma unroll
        for (int mi = 0; mi < 2; ++mi) {
          const int r = wr * 64 + mi * 32 + l31;
          a[mi] = *(const i32x4*)(S + r * LSTR + ((sr ^ (r & 7)) << 4));
        }
#pragma unroll
        for (int ni = 0; ni < 2; ++ni) {
          const int r = wc * 64 + ni * 32 + l31;
          b[ni] = *(const i32x4*)(S + 20480 + r * LSTR + ((sr ^ (r & 7)) << 4));
        }
#pragma unroll
        for (int mi = 0; mi < 2; ++mi)
#pragma unroll
          for (int ni = 0; ni < 2; ++ni)
            acc[mi][ni] = __builtin_amdgcn_mfma_i32_32x32x32_i8(a[mi], b[ni], acc[mi][ni], 0, 0, 0);
      }
      __builtin_amdgcn_s_setprio(0);
    }

    // ---- epilogue: 2 stages of 64 cols each ----
#pragma unroll 1
    for (int st = 0; st < 2; ++st) {
      __syncthreads();                        // prior S/Kbuf readers done
      if (wc == st) {                         // 2 waves write 128 rows x 64 cols
#pragma unroll
        for (int mi = 0; mi < 2; ++mi)
#pragma unroll
          for (int ni = 0; ni < 2; ++ni) {
            const int col = ni * 32 + l31;    // dword col within stage
            const int mn = mn_[ni];
#pragma unroll
            for (int r = 0; r < 16; ++r) {
              const int row = wr * 64 + mi * 32 + 4 * kh + (r & 3) + 8 * (r >> 2);
              Kbuf[row * 64 + (col ^ ((row & 15) << 2))] = mn - 2 * acc[mi][ni][r];
            }
          }
      }
      __syncthreads();
      {                                       // 256-thread scan: top-6 of 32
        const int row = t & 127, sub = t >> 7;
        unsigned tk[TOPC];
#pragma unroll
        for (int s = 0; s < TOPC; ++s) tk[s] = 0xFFFFFFFFu;
#pragma unroll
        for (int q = 0; q < 8; ++q) {
          const int cl = sub * 32 + q * 4;
          const i32x4 v = *(const i32x4*)(Kbuf + row * 64 + (cl ^ ((row & 15) << 2)));
#pragma unroll
          for (int e = 0; e < 4; ++e) {
            // pack: 18-bit biased key | 14-bit global j (monotone in key)
            const unsigned p = (((unsigned)(v[e] + (1 << 25)) >> 11) << 14)
                               | (unsigned)(j0 + st * 64 + cl + e);
            if (p < tk[0]) {                  // replace max, bubble (sorted desc)
              tk[0] = p;
#pragma unroll
              for (int s = 0; s < TOPC - 1; ++s) {
                const unsigned hi = tk[s] > tk[s + 1] ? tk[s] : tk[s + 1];
                const unsigned lo = tk[s] > tk[s + 1] ? tk[s + 1] : tk[s];
                tk[s] = hi; tk[s + 1] = lo;
              }
            }
          }
        }
#pragma unroll
        for (int s = 0; s < TOPC; ++s) stage6[t * TOPC + s] = tk[s];
      }
      __syncthreads();
      if (t < 128) {                          // rank-count merge (no runtime reg idx)
        const size_t base = (size_t)(r0 + t) * NCAND + (size_t)(pglob * 2 + st) * TOPC;
#pragma unroll
        for (int i2 = 0; i2 < TOPC; ++i2) {
          const unsigned va = stage6[t * TOPC + i2];
          int ca = (TOPC - 1) - i2;           // # smaller within own desc-sorted list
#pragma unroll
          for (int j2 = 0; j2 < TOPC; ++j2) ca += (stage6[(t + 128) * TOPC + j2] < va);
          if (ca < TOPC) cand[base + ca] = va;
          const unsigned vb = stage6[(t + 128) * TOPC + i2];
          int cb = (TOPC - 1) - i2;
#pragma unroll
          for (int j2 = 0; j2 < TOPC; ++j2) cb += (stage6[t * TOPC + j2] < vb);
          if (cb < TOPC) cand[base + cb] = vb;
        }
      }
    }
    __syncthreads();                          // merge reads done before next job
  }
}

// ---- merge 1536 candidates -> top-16 -> fp64 rerank -> top-9 (R10-proven) ----
__global__ void k_rerank(const float* __restrict__ xf, const float* __restrict__ mb,
                         const unsigned int* __restrict__ cand,
                         int* __restrict__ idx9, double* __restrict__ dsv) {
  const int n = blockIdx.x, t = threadIdx.x;
  __shared__ float    xs[DIM];
  __shared__ unsigned cs[NCAND];
  __shared__ unsigned sel[TRR];
  __shared__ double dpart[256];
  __shared__ double d2s[TRR];
  __shared__ double dist_s[TRR];
  __shared__ int    rank_s[TRR];

  const float* xrow = xf + (size_t)n * DIM;
  for (int c = t; c < DIM; c += 256) xs[c] = xrow[c];
  const size_t cb = (size_t)n * NCAND;
  for (int s = t; s < NCAND; s += 256) cs[s] = cand[cb + s];
  __syncthreads();

  if (t < 64) {  // wave 0: 64 lanes x 24 items, 16 extract-min rounds
    unsigned ck[24];
#pragma unroll
    for (int s = 0; s < 24; ++s) ck[s] = cs[t + 64 * s];
    for (int it = 0; it < TRR; ++it) {
      unsigned best = ck[0];
#pragma unroll
      for (int s = 1; s < 24; ++s) best = best < ck[s] ? best : ck[s];
#pragma unroll
      for (int off = 32; off >= 1; off >>= 1) {
        const unsigned o = (unsigned)__shfl_xor((int)best, off);
        best = best < o ? best : o;
      }
      if (t == 0) sel[it] = best;
#pragma unroll
      for (int s = 0; s < 24; ++s) if (ck[s] == best) ck[s] = 0xFFFFFFFFu;
    }
  }
  __syncthreads();
  {
    const int s = t >> 4, l16 = t & 15;
    const int j = (int)(sel[s] & 16383u);
    const float* mrow = mb + (size_t)j * DIM;
    double a = 0.0;
    for (int i = 0; i < 64; ++i) {
      const int c = l16 + (i << 4);
      const double d = (double)xs[c] - (double)mrow[c];
      a += d * d;
    }
    dpart[t] = a;
  }
  __syncthreads();
  if (t < TRR) {
    double v = 0.0;
    for (int i = 0; i < 16; ++i) v += dpart[t * 16 + i];
    d2s[t] = v;
    dist_s[t] = sqrt(v < 1e-12 ? 1e-12 : v);
  }
  __syncthreads();
  if (t < TRR) {
    const double v = d2s[t]; const int id = (int)(sel[t] & 16383u);
    int r = 0;
    for (int u = 0; u < TRR; ++u) {
      const double vu = d2s[u];
      const int idu = (int)(sel[u] & 16383u);
      if (vu < v || (vu == v && idu < id)) ++r;
    }
    rank_s[t] = r;
    if (r < KNN) idx9[n * KNN + r] = id;
  }
  __syncthreads();
  if (t == 0) {
    double sum = 0.0;
    for (int u = 0; u < TRR; ++u) if (rank_s[u] < KNN) sum += dist_s[u];
    dsv[n] = sum * (1.0 / KNN);
  }
}

// ---- global mean/std of per-row mean distance (R10-proven) ----
__global__ void k_dsstats(const double* __restrict__ dsv, double* __restrict__ stats) {
  __shared__ double red[1024];
  const int t = threadIdx.x;
  double s = 0.0;
  for (int i = t; i < N_ROWS; i += 1024) s += dsv[i];
  red[t] = s; __syncthreads();
  for (int o = 512; o >= 1; o >>= 1) { if (t < o) red[t] += red[t + o]; __syncthreads(); }
  const double mean = red[0] / (double)N_ROWS;
  __syncthreads();
  double v = 0.0;
  for (int i = t; i < N_ROWS; i += 1024) { const double d = dsv[i] - mean; v += d * d; }
  red[t] = v; __syncthreads();
  for (int o = 512; o >= 1; o >>= 1) { if (t < o) red[t] += red[t + o]; __syncthreads(); }
  if (t == 0) {
    const double fullstd = sqrt(red[0] * (double)DIM / ((double)N_ROWS * DIM - 1.0));
    stats[0] = mean;
    stats[1] = fullstd + 1e-8;
  }
}

// ---- influence, row-norm, sigmoid noise, fused NCHW write + maps (R10) ----
__global__ void k_final(const float* __restrict__ xf, const float* __restrict__ mb,
                        const float* __restrict__ iw, const float* __restrict__ dwp,
                        const float* __restrict__ eps, const int* __restrict__ idx9,
                        const double* __restrict__ dsv, const double* __restrict__ stats,
                        float* __restrict__ out) {
  const int n = blockIdx.x, t = threadIdx.x;
  __shared__ float xs[DIM];
  __shared__ int js[KNN];
  __shared__ float rs1[4], rs2[4];
  const float* xrow = xf + (size_t)n * DIM;
  for (int c = t; c < DIM; c += 256) xs[c] = xrow[c];
  if (t < KNN) js[t] = idx9[n * KNN + t];
  __syncthreads();

  float infl[4];
  float s1 = 0.f, s2 = 0.f;
#pragma unroll
  for (int q = 0; q < 4; ++q) {
    const int c = t + q * 256;
    const float x = xs[c];
    float a = 0.f;
#pragma unroll
    for (int k = 0; k < KNN; ++k) a += fabsf(x - mb[(size_t)js[k] * DIM + c]);
    const float v = a * (1.0f / KNN) * iw[c];
    infl[q] = v; s1 += v; s2 += v * v;
  }
#pragma unroll
  for (int o = 32; o >= 1; o >>= 1) { s1 += __shfl_down(s1, o); s2 += __shfl_down(s2, o); }
  if ((t & 63) == 0) { rs1[t >> 6] = s1; rs2[t >> 6] = s2; }
  __syncthreads();
  const float sum = rs1[0] + rs1[1] + rs1[2] + rs1[3];
  const float sq  = rs2[0] + rs2[1] + rs2[2] + rs2[3];
  const float mean = sum * (1.0f / DIM);
  float var = (sq - (float)DIM * mean * mean) * (1.0f / (DIM - 1));
  var = fmaxf(var, 0.f);
  const float inv = 1.0f / (sqrtf(var) + 1e-8f);
  const float dn = (float)(((double)dsv[n] - stats[0]) / stats[1]);
  const float zb = dwp[0] * dn;

  const int b = n / 784, hw = n % 784;
  float* op = out + (size_t)b * (1024 * 784) + hw;
  const float* ep = eps + (size_t)n * DIM;
  float si = 0.f, sn = 0.f;
#pragma unroll
  for (int q = 0; q < 4; ++q) {
    const int c = t + q * 256;
    const float v = infl[q];
    const float z = (v - mean) * inv + zb;
    const float ns = 0.01f + 0.49f / (1.0f + expf(-z));
    op[(size_t)c * 784] = xs[c] + ep[c] * ns;   // L2 absorbs the n-adjacent scatter
    si += v; sn += ns;
  }
  __syncthreads();  // rs1/rs2 reads above complete before reuse
#pragma unroll
  for (int o = 32; o >= 1; o >>= 1) { si += __shfl_down(si, o); sn += __shfl_down(sn, o); }
  if ((t & 63) == 0) { rs1[t >> 6] = si; rs2[t >> 6] = sn; }
  __syncthreads();
  if (t == 0) {
    out[6422528 + n]        = (rs1[0] + rs1[1] + rs1[2] + rs1[3]) * (1.0f / DIM);
    out[6422528 + 6272 + n] = (rs2[0] + rs2[1] + rs2[2] + rs2[3]) * (1.0f / DIM);
  }
}

extern "C" void kernel_launch(void* const* d_in, const int* in_sizes, int n_in,
                              void* d_out, int out_size, void* d_ws, size_t ws_size,
                              hipStream_t stream) {
  (void)in_sizes; (void)n_in; (void)out_size; (void)ws_size;
  const float* feat = (const float*)d_in[0];
  const float* mb   = (const float*)d_in[1];
  const float* iw   = (const float*)d_in[2];
  const float* dw   = (const float*)d_in[3];
  const float* eps  = (const float*)d_in[4];
  float* out = (float*)d_out;

  char* p = (char*)d_ws;
  float* xf = (float*)p;                     p += (size_t)N_ROWS * DIM * 4;
  signed char* xq = (signed char*)p;         p += (size_t)N_ROWS * DIM;
  signed char* mq = (signed char*)p;         p += (size_t)M_ROWS * DIM;
  int* mni = (int*)p;                        p += (size_t)M_ROWS * 4;
  unsigned int* cand = (unsigned int*)p;     p += (size_t)N_ROWS * NCAND * 4;
  int* idx9 = (int*)p;                       p += (size_t)N_ROWS * KNN * 4;
  p = (char*)(((uintptr_t)p + 255) & ~(uintptr_t)255);
  double* dsv = (double*)p;                  p += (size_t)N_ROWS * 8;
  double* stats = (double*)p;                p += 64;
  // total ~88 MB of d_ws

  k_prep_x<<<6272, 256, 0, stream>>>(feat, xf, xq);
  k_prep_m<<<M_ROWS, 256, 0, stream>>>(mb, mq, mni);
  k_score<<<1024, 256, 0, stream>>>(xq, mq, mni, cand);
  k_rerank<<<N_ROWS, 256, 0, stream>>>(xf, mb, cand, idx9, dsv);
  k_dsstats<<<1, 1024, 0, stream>>>(dsv, stats);
  k_final<<<N_ROWS, 256, 0, stream>>>(xf, mb, iw, dw, eps, idx9, dsv, stats, out);
}

// Round 17
// 406.599 us; speedup vs baseline: 1.5308x; 1.5308x over previous
//
#include <hip/hip_runtime.h>
#include <hip/hip_bf16.h>
#include <stdint.h>

// Problem dims (fixed instance)
#define N_ROWS 6272      // B*H*W = 8*28*28, = 49*128 exactly
#define DIM    1024
#define M_ROWS 16384
#define KNN    9
#define BMS    128       // score tile M
#define BNS    128       // score tile N (= j-panel width)
#define NPANEL 128       // global 128-col panel count
#define TOPC   6         // candidates kept per (row, panel, col-half)
#define NCAND  (NPANEL * 2 * TOPC)   // 1536 per row
#define TRR    16        // rerank count
#define LSTR   160       // LDS row stride (bytes): 10*16B granules

typedef __attribute__((ext_vector_type(4))) float f32x4;
typedef __attribute__((ext_vector_type(4))) int   i32x4;
typedef __attribute__((ext_vector_type(16))) int  i32x16;

#define QSCALE 31.75f    // 127/4: clamp N(0,1) data to +-4, round to int8

__device__ __forceinline__ int quant8(float v) {
  return __float2int_rn(fminf(fmaxf(v, -4.f), 4.f) * QSCALE);
}

// ---- x transpose: 32x32 LDS tiles, coalesced read (hw) + write (c) ----
__global__ void k_prep_x(const float* __restrict__ feat,
                         float* __restrict__ xf, signed char* __restrict__ xq) {
  __shared__ float tile[32][33];
  const int ct = blockIdx.x & 31, nt = blockIdx.x >> 5;  // 32 c-tiles x 196 n-tiles
  const int c0 = ct * 32, n0 = nt * 32;
  const int tx = threadIdx.x & 31, ty = threadIdx.x >> 5; // ty in [0,8)
  {
    const int n = n0 + tx;
    const int b = n / 784, hw = n % 784;
    const float* src = feat + (size_t)b * 802816 + hw;
#pragma unroll
    for (int q = 0; q < 4; ++q)
      tile[ty + q * 8][tx] = src[(size_t)(c0 + ty + q * 8) * 784];
  }
  __syncthreads();
#pragma unroll
  for (int q = 0; q < 4; ++q) {
    const int nn = n0 + ty + q * 8;
    const int cc = c0 + tx;
    const float v = tile[tx][ty + q * 8];
    xf[(size_t)nn * DIM + cc] = v;
    xq[(size_t)nn * DIM + cc] = (signed char)quant8(v);
  }
}

// ---- memory bank: int8 copy + integer row squared norms (R10-proven) ----
__global__ void k_prep_m(const float* __restrict__ mb,
                         signed char* __restrict__ mq, int* __restrict__ mni) {
  const int j = blockIdx.x;
  const int t = threadIdx.x;
  const float* src = mb + (size_t)j * DIM;
  signed char* dst = mq + (size_t)j * DIM;
  int s = 0;
  for (int c = t; c < DIM; c += 256) {
    const int q = quant8(src[c]);
    dst[c] = (signed char)q;
    s += q * q;
  }
  __shared__ int red[4];
#pragma unroll
  for (int o = 32; o >= 1; o >>= 1) s += __shfl_down(s, o);
  if ((t & 63) == 0) red[t >> 6] = s;
  __syncthreads();
  if (t == 0) mni[j] = red[0] + red[1] + red[2] + red[3];
}

// ---- int8 MFMA distance GEMM: 40 KB LDS, natural 4 blocks/CU TLP ----
// 1024 blocks = 8 XCD x 16 panels (2 MB i8 B resident/XCD) x 8 agroups.
// Single-buffer K-staging (sync, ds_write, sync, issue-next, MFMA);
// 2-stage epilogue: 128x64 swizzled Kbuf, top-6-of-32 scan + rank-count merge.
// launch_bounds(256,2): allocator free to 128 VGPR (R16's (256,4) forced 64
// -> spills); 128 VGPR + 40 KB LDS both permit 4 blocks/CU naturally.
__launch_bounds__(256, 2)
__global__ void k_score(const signed char* __restrict__ xq,
                        const signed char* __restrict__ mq,
                        const int* __restrict__ mni,
                        unsigned int* __restrict__ cand) {
  __shared__ signed char S[40960];            // A @0 (20 KB) | B @20480 (20 KB)
  int* Kbuf = (int*)S;                        // 128 x 64 i32 = 32 KB (epilogue alias)
  unsigned* stage6 = (unsigned*)(S + 32768);  // 256 x 6 u32 = 6 KB (epilogue alias)

  const int bx = blockIdx.x;
  const int xcd = bx & 7, i = bx >> 3;        // dispatch round-robins XCDs
  const int panel = i & 15, agroup = i >> 4;  // 16 panels x 8 agroups per XCD
  const int j0 = xcd * 2048 + panel * BNS;
  const int pglob = xcd * 16 + panel;         // [0,128)

  const int t = threadIdx.x;
  const int lane = t & 63, w = t >> 6;
  const int wr = w >> 1, wc = w & 1;          // wave grid 2 x 2
  const int l31 = lane & 31, kh = lane >> 5;

  // staging chunk geometry: 4 x 16B per operand per K-tile per thread
  int srcOff[4], ldsOff[4];
#pragma unroll
  for (int cpy = 0; cpy < 4; ++cpy) {
    const int c = cpy * 256 + t;              // [0,1024)
    const int row = c >> 3, s = c & 7;
    srcOff[cpy] = row * DIM + s * 16;
    ldsOff[cpy] = row * LSTR + ((s ^ (row & 7)) << 4);
  }
  const signed char* bBase = mq + (size_t)j0 * DIM;

  int mn_[2];                                 // col-norms for this thread's cols
#pragma unroll
  for (int ni = 0; ni < 2; ++ni) mn_[ni] = mni[j0 + wc * 64 + ni * 32 + l31];

  const int tcount = (agroup == 0) ? 7 : 6;   // tiles = agroup + 8k < 49
#pragma unroll 1
  for (int k7 = 0; k7 < tcount; ++k7) {
    const int tile = agroup + 8 * k7;
    const int r0 = tile * BMS;
    const signed char* aBase = xq + (size_t)r0 * DIM;

    i32x16 acc[2][2];
#pragma unroll
    for (int mi = 0; mi < 2; ++mi)
#pragma unroll
      for (int ni = 0; ni < 2; ++ni)
#pragma unroll
        for (int r = 0; r < 16; ++r) acc[mi][ni][r] = 0;

    i32x4 ra[4], rb[4];
    // job prologue: issue K-tile 0 loads (overlaps previous job's epilogue)
#pragma unroll
    for (int cpy = 0; cpy < 4; ++cpy) {
      ra[cpy] = *(const i32x4*)(aBase + srcOff[cpy]);
      rb[cpy] = *(const i32x4*)(bBase + srcOff[cpy]);
    }

#pragma unroll 1
    for (int kt = 0; kt < 8; ++kt) {
      __syncthreads();                        // S free; drains ra/rb loads
#pragma unroll
      for (int cpy = 0; cpy < 4; ++cpy) {
        *(i32x4*)(S + ldsOff[cpy]) = ra[cpy];
        *(i32x4*)(S + 20480 + ldsOff[cpy]) = rb[cpy];
      }
      __syncthreads();                        // tile kt resident for ALL waves
      if (kt < 7) {                           // issue next-tile loads early
        const int kk = (kt + 1) * 128;
#pragma unroll
        for (int cpy = 0; cpy < 4; ++cpy) {
          ra[cpy] = *(const i32x4*)(aBase + srcOff[cpy] + kk);
          rb[cpy] = *(const i32x4*)(bBase + srcOff[cpy] + kk);
        }
      }
      __builtin_amdgcn_s_setprio(1);
#pragma unroll
      for (int ks = 0; ks < 4; ++ks) {
        const int sr = 2 * ks + kh;
        i32x4 a[2], b[2];
#pragma unroll
        for (int mi = 0; mi < 2; ++mi) {
          const int r = wr * 64 + mi * 32 + l31;
          a[mi] = *(const i32x4*)(S + r * LSTR + ((sr ^ (r & 7)) << 4));
        }
#pragma unroll
        for (int ni = 0; ni < 2; ++ni) {
          const int r = wc * 64 + ni * 32 + l31;
          b[ni] = *(const i32x4*)(S + 20480 + r * LSTR + ((sr ^ (r & 7)) << 4));
        }
#pragma unroll
        for (int mi = 0; mi < 2; ++mi)
#pragma unroll
          for (int ni = 0; ni < 2; ++ni)
            acc[mi][ni] = __builtin_amdgcn_mfma_i32_32x32x32_i8(a[mi], b[ni], acc[mi][ni], 0, 0, 0);
      }
      __builtin_amdgcn_s_setprio(0);
    }

    // ---- epilogue: 2 stages of 64 cols each ----
#pragma unroll 1
    for (int st = 0; st < 2; ++st) {
      __syncthreads();                        // prior S/Kbuf readers done
      if (wc == st) {                         // 2 waves write 128 rows x 64 cols
#pragma unroll
        for (int mi = 0; mi < 2; ++mi)
#pragma unroll
          for (int ni = 0; ni < 2; ++ni) {
            const int col = ni * 32 + l31;    // dword col within stage
            const int mn = mn_[ni];
#pragma unroll
            for (int r = 0; r < 16; ++r) {
              const int row = wr * 64 + mi * 32 + 4 * kh + (r & 3) + 8 * (r >> 2);
              Kbuf[row * 64 + (col ^ ((row & 15) << 2))] = mn - 2 * acc[mi][ni][r];
            }
          }
      }
      __syncthreads();
      {                                       // 256-thread scan: top-6 of 32
        const int row = t & 127, sub = t >> 7;
        unsigned tk[TOPC];
#pragma unroll
        for (int s = 0; s < TOPC; ++s) tk[s] = 0xFFFFFFFFu;
#pragma unroll
        for (int q = 0; q < 8; ++q) {
          const int cl = sub * 32 + q * 4;
          const i32x4 v = *(const i32x4*)(Kbuf + row * 64 + (cl ^ ((row & 15) << 2)));
#pragma unroll
          for (int e = 0; e < 4; ++e) {
            // pack: 18-bit biased key | 14-bit global j (monotone in key)
            const unsigned p = (((unsigned)(v[e] + (1 << 25)) >> 11) << 14)
                               | (unsigned)(j0 + st * 64 + cl + e);
            if (p < tk[0]) {                  // replace max, bubble (sorted desc)
              tk[0] = p;
#pragma unroll
              for (int s = 0; s < TOPC - 1; ++s) {
                const unsigned hi = tk[s] > tk[s + 1] ? tk[s] : tk[s + 1];
                const unsigned lo = tk[s] > tk[s + 1] ? tk[s + 1] : tk[s];
                tk[s] = hi; tk[s + 1] = lo;
              }
            }
          }
        }
#pragma unroll
        for (int s = 0; s < TOPC; ++s) stage6[t * TOPC + s] = tk[s];
      }
      __syncthreads();
      if (t < 128) {                          // rank-count merge (no runtime reg idx)
        const size_t base = (size_t)(r0 + t) * NCAND + (size_t)(pglob * 2 + st) * TOPC;
#pragma unroll
        for (int i2 = 0; i2 < TOPC; ++i2) {
          const unsigned va = stage6[t * TOPC + i2];
          int ca = (TOPC - 1) - i2;           // # smaller within own desc-sorted list
#pragma unroll
          for (int j2 = 0; j2 < TOPC; ++j2) ca += (stage6[(t + 128) * TOPC + j2] < va);
          if (ca < TOPC) cand[base + ca] = va;
          const unsigned vb = stage6[(t + 128) * TOPC + i2];
          int cb = (TOPC - 1) - i2;
#pragma unroll
          for (int j2 = 0; j2 < TOPC; ++j2) cb += (stage6[t * TOPC + j2] < vb);
          if (cb < TOPC) cand[base + cb] = vb;
        }
      }
    }
    __syncthreads();                          // merge reads done before next job
  }
}

// ---- merge 1536 candidates -> top-16 -> fp64 rerank -> top-9 (R10-proven) ----
__global__ void k_rerank(const float* __restrict__ xf, const float* __restrict__ mb,
                         const unsigned int* __restrict__ cand,
                         int* __restrict__ idx9, double* __restrict__ dsv) {
  const int n = blockIdx.x, t = threadIdx.x;
  __shared__ float    xs[DIM];
  __shared__ unsigned cs[NCAND];
  __shared__ unsigned sel[TRR];
  __shared__ double dpart[256];
  __shared__ double d2s[TRR];
  __shared__ double dist_s[TRR];
  __shared__ int    rank_s[TRR];

  const float* xrow = xf + (size_t)n * DIM;
  for (int c = t; c < DIM; c += 256) xs[c] = xrow[c];
  const size_t cb = (size_t)n * NCAND;
  for (int s = t; s < NCAND; s += 256) cs[s] = cand[cb + s];
  __syncthreads();

  if (t < 64) {  // wave 0: 64 lanes x 24 items, 16 extract-min rounds
    unsigned ck[24];
#pragma unroll
    for (int s = 0; s < 24; ++s) ck[s] = cs[t + 64 * s];
    for (int it = 0; it < TRR; ++it) {
      unsigned best = ck[0];
#pragma unroll
      for (int s = 1; s < 24; ++s) best = best < ck[s] ? best : ck[s];
#pragma unroll
      for (int off = 32; off >= 1; off >>= 1) {
        const unsigned o = (unsigned)__shfl_xor((int)best, off);
        best = best < o ? best : o;
      }
      if (t == 0) sel[it] = best;
#pragma unroll
      for (int s = 0; s < 24; ++s) if (ck[s] == best) ck[s] = 0xFFFFFFFFu;
    }
  }
  __syncthreads();
  {
    const int s = t >> 4, l16 = t & 15;
    const int j = (int)(sel[s] & 16383u);
    const float* mrow = mb + (size_t)j * DIM;
    double a = 0.0;
    for (int i = 0; i < 64; ++i) {
      const int c = l16 + (i << 4);
      const double d = (double)xs[c] - (double)mrow[c];
      a += d * d;
    }
    dpart[t] = a;
  }
  __syncthreads();
  if (t < TRR) {
    double v = 0.0;
    for (int i = 0; i < 16; ++i) v += dpart[t * 16 + i];
    d2s[t] = v;
    dist_s[t] = sqrt(v < 1e-12 ? 1e-12 : v);
  }
  __syncthreads();
  if (t < TRR) {
    const double v = d2s[t]; const int id = (int)(sel[t] & 16383u);
    int r = 0;
    for (int u = 0; u < TRR; ++u) {
      const double vu = d2s[u];
      const int idu = (int)(sel[u] & 16383u);
      if (vu < v || (vu == v && idu < id)) ++r;
    }
    rank_s[t] = r;
    if (r < KNN) idx9[n * KNN + r] = id;
  }
  __syncthreads();
  if (t == 0) {
    double sum = 0.0;
    for (int u = 0; u < TRR; ++u) if (rank_s[u] < KNN) sum += dist_s[u];
    dsv[n] = sum * (1.0 / KNN);
  }
}

// ---- global mean/std of per-row mean distance (R10-proven) ----
__global__ void k_dsstats(const double* __restrict__ dsv, double* __restrict__ stats) {
  __shared__ double red[1024];
  const int t = threadIdx.x;
  double s = 0.0;
  for (int i = t; i < N_ROWS; i += 1024) s += dsv[i];
  red[t] = s; __syncthreads();
  for (int o = 512; o >= 1; o >>= 1) { if (t < o) red[t] += red[t + o]; __syncthreads(); }
  const double mean = red[0] / (double)N_ROWS;
  __syncthreads();
  double v = 0.0;
  for (int i = t; i < N_ROWS; i += 1024) { const double d = dsv[i] - mean; v += d * d; }
  red[t] = v; __syncthreads();
  for (int o = 512; o >= 1; o >>= 1) { if (t < o) red[t] += red[t + o]; __syncthreads(); }
  if (t == 0) {
    const double fullstd = sqrt(red[0] * (double)DIM / ((double)N_ROWS * DIM - 1.0));
    stats[0] = mean;
    stats[1] = fullstd + 1e-8;
  }
}

// ---- influence, row-norm, sigmoid noise, fused NCHW write + maps (R10) ----
__global__ void k_final(const float* __restrict__ xf, const float* __restrict__ mb,
                        const float* __restrict__ iw, const float* __restrict__ dwp,
                        const float* __restrict__ eps, const int* __restrict__ idx9,
                        const double* __restrict__ dsv, const double* __restrict__ stats,
                        float* __restrict__ out) {
  const int n = blockIdx.x, t = threadIdx.x;
  __shared__ float xs[DIM];
  __shared__ int js[KNN];
  __shared__ float rs1[4], rs2[4];
  const float* xrow = xf + (size_t)n * DIM;
  for (int c = t; c < DIM; c += 256) xs[c] = xrow[c];
  if (t < KNN) js[t] = idx9[n * KNN + t];
  __syncthreads();

  float infl[4];
  float s1 = 0.f, s2 = 0.f;
#pragma unroll
  for (int q = 0; q < 4; ++q) {
    const int c = t + q * 256;
    const float x = xs[c];
    float a = 0.f;
#pragma unroll
    for (int k = 0; k < KNN; ++k) a += fabsf(x - mb[(size_t)js[k] * DIM + c]);
    const float v = a * (1.0f / KNN) * iw[c];
    infl[q] = v; s1 += v; s2 += v * v;
  }
#pragma unroll
  for (int o = 32; o >= 1; o >>= 1) { s1 += __shfl_down(s1, o); s2 += __shfl_down(s2, o); }
  if ((t & 63) == 0) { rs1[t >> 6] = s1; rs2[t >> 6] = s2; }
  __syncthreads();
  const float sum = rs1[0] + rs1[1] + rs1[2] + rs1[3];
  const float sq  = rs2[0] + rs2[1] + rs2[2] + rs2[3];
  const float mean = sum * (1.0f / DIM);
  float var = (sq - (float)DIM * mean * mean) * (1.0f / (DIM - 1));
  var = fmaxf(var, 0.f);
  const float inv = 1.0f / (sqrtf(var) + 1e-8f);
  const float dn = (float)(((double)dsv[n] - stats[0]) / stats[1]);
  const float zb = dwp[0] * dn;

  const int b = n / 784, hw = n % 784;
  float* op = out + (size_t)b * (1024 * 784) + hw;
  const float* ep = eps + (size_t)n * DIM;
  float si = 0.f, sn = 0.f;
#pragma unroll
  for (int q = 0; q < 4; ++q) {
    const int c = t + q * 256;
    const float v = infl[q];
    const float z = (v - mean) * inv + zb;
    const float ns = 0.01f + 0.49f / (1.0f + expf(-z));
    op[(size_t)c * 784] = xs[c] + ep[c] * ns;   // L2 absorbs the n-adjacent scatter
    si += v; sn += ns;
  }
  __syncthreads();  // rs1/rs2 reads above complete before reuse
#pragma unroll
  for (int o = 32; o >= 1; o >>= 1) { si += __shfl_down(si, o); sn += __shfl_down(sn, o); }
  if ((t & 63) == 0) { rs1[t >> 6] = si; rs2[t >> 6] = sn; }
  __syncthreads();
  if (t == 0) {
    out[6422528 + n]        = (rs1[0] + rs1[1] + rs1[2] + rs1[3]) * (1.0f / DIM);
    out[6422528 + 6272 + n] = (rs2[0] + rs2[1] + rs2[2] + rs2[3]) * (1.0f / DIM);
  }
}

extern "C" void kernel_launch(void* const* d_in, const int* in_sizes, int n_in,
                              void* d_out, int out_size, void* d_ws, size_t ws_size,
                              hipStream_t stream) {
  (void)in_sizes; (void)n_in; (void)out_size; (void)ws_size;
  const float* feat = (const float*)d_in[0];
  const float* mb   = (const float*)d_in[1];
  const float* iw   = (const float*)d_in[2];
  const float* dw   = (const float*)d_in[3];
  const float* eps  = (const float*)d_in[4];
  float* out = (float*)d_out;

  char* p = (char*)d_ws;
  float* xf = (float*)p;                     p += (size_t)N_ROWS * DIM * 4;
  signed char* xq = (signed char*)p;         p += (size_t)N_ROWS * DIM;
  signed char* mq = (signed char*)p;         p += (size_t)M_ROWS * DIM;
  int* mni = (int*)p;                        p += (size_t)M_ROWS * 4;
  unsigned int* cand = (unsigned int*)p;     p += (size_t)N_ROWS * NCAND * 4;
  int* idx9 = (int*)p;                       p += (size_t)N_ROWS * KNN * 4;
  p = (char*)(((uintptr_t)p + 255) & ~(uintptr_t)255);
  double* dsv = (double*)p;                  p += (size_t)N_ROWS * 8;
  double* stats = (double*)p;                p += 64;
  // total ~88 MB of d_ws

  k_prep_x<<<6272, 256, 0, stream>>>(feat, xf, xq);
  k_prep_m<<<M_ROWS, 256, 0, stream>>>(mb, mq, mni);
  k_score<<<1024, 256, 0, stream>>>(xq, mq, mni, cand);
  k_rerank<<<N_ROWS, 256, 0, stream>>>(xf, mb, cand, idx9, dsv);
  k_dsstats<<<1, 1024, 0, stream>>>(dsv, stats);
  k_final<<<N_ROWS, 256, 0, stream>>>(xf, mb, iw, dw, eps, idx9, dsv, stats, out);
}

// Round 18
// 381.735 us; speedup vs baseline: 1.6305x; 1.0651x over previous
//
#include <hip/hip_runtime.h>
#include <hip/hip_bf16.h>
#include <stdint.h>

// Problem dims (fixed instance)
#define N_ROWS 6272      // B*H*W = 8*28*28, = 49*128 exactly
#define DIM    1024
#define M_ROWS 16384
#define KNN    9
#define BMS    128       // score tile M
#define BNS    128       // score tile N (= j-panel width)
#define NPANEL 128       // global 128-col panel count
#define TOPC   6         // candidates kept per (row, panel, col-half)
#define NCAND  (NPANEL * 2 * TOPC)   // 1536 per row
#define TRR    16        // rerank count
#define LSTR   160       // LDS row stride (bytes): 10*16B granules

typedef __attribute__((ext_vector_type(4))) float f32x4;
typedef __attribute__((ext_vector_type(4))) int   i32x4;
typedef __attribute__((ext_vector_type(16))) int  i32x16;

#define QSCALE 31.75f    // 127/4: clamp N(0,1) data to +-4, round to int8

__device__ __forceinline__ int quant8(float v) {
  return __float2int_rn(fminf(fmaxf(v, -4.f), 4.f) * QSCALE);
}

// Kbuf swizzle: 128x128 dwords, 4-dword granule XOR
__device__ __forceinline__ int kswz(int row, int col) {
  return col ^ ((row & 7) << 2) ^ (((row >> 3) & 1) << 5);
}

// ---- x transpose: 32x32 LDS tiles, coalesced read (hw) + write (c) ----
__global__ void k_prep_x(const float* __restrict__ feat,
                         float* __restrict__ xf, signed char* __restrict__ xq) {
  __shared__ float tile[32][33];
  const int ct = blockIdx.x & 31, nt = blockIdx.x >> 5;  // 32 c-tiles x 196 n-tiles
  const int c0 = ct * 32, n0 = nt * 32;
  const int tx = threadIdx.x & 31, ty = threadIdx.x >> 5; // ty in [0,8)
  {
    const int n = n0 + tx;
    const int b = n / 784, hw = n % 784;
    const float* src = feat + (size_t)b * 802816 + hw;
#pragma unroll
    for (int q = 0; q < 4; ++q)
      tile[ty + q * 8][tx] = src[(size_t)(c0 + ty + q * 8) * 784];
  }
  __syncthreads();
#pragma unroll
  for (int q = 0; q < 4; ++q) {
    const int nn = n0 + ty + q * 8;
    const int cc = c0 + tx;
    const float v = tile[tx][ty + q * 8];
    xf[(size_t)nn * DIM + cc] = v;
    xq[(size_t)nn * DIM + cc] = (signed char)quant8(v);
  }
}

// ---- memory bank: int8 copy + integer row squared norms (R10-proven) ----
__global__ void k_prep_m(const float* __restrict__ mb,
                         signed char* __restrict__ mq, int* __restrict__ mni) {
  const int j = blockIdx.x;
  const int t = threadIdx.x;
  const float* src = mb + (size_t)j * DIM;
  signed char* dst = mq + (size_t)j * DIM;
  int s = 0;
  for (int c = t; c < DIM; c += 256) {
    const int q = quant8(src[c]);
    dst[c] = (signed char)q;
    s += q * q;
  }
  __shared__ int red[4];
#pragma unroll
  for (int o = 32; o >= 1; o >>= 1) s += __shfl_down(s, o);
  if ((t & 63) == 0) red[t >> 6] = s;
  __syncthreads();
  if (t == 0) mni[j] = red[0] + red[1] + red[2] + red[3];
}

// ---- int8 MFMA distance GEMM (R11-proven, 213 us): single launch,
// 512 blocks = 8 XCD x 16 panels (2 MB i8 B resident/XCD) x 4 agroups.
// Reg-staged double-buffer, one barrier per K-tile, 160B LDS rows.
__launch_bounds__(256, 2)
__global__ void k_score(const signed char* __restrict__ xq,
                        const signed char* __restrict__ mq,
                        const int* __restrict__ mni,
                        unsigned int* __restrict__ cand) {
  __shared__ signed char S[81920];   // A0 @0 | A1 @20480 | B0 @40960 | B1 @61440
  int* Kbuf = (int*)S;               // 128x128 i32 = 64 KB alias (epilogue)

  const int bx = blockIdx.x;
  const int xcd = bx & 7, i = bx >> 3;      // dispatch round-robins XCDs
  const int panel = i & 15, agroup = i >> 4; // 16 panels x 4 agroups per XCD
  const int j0 = xcd * 2048 + panel * BNS;
  const int pglob = xcd * 16 + panel;        // [0,128)

  const int t = threadIdx.x;
  const int lane = t & 63, w = t >> 6;
  const int wr = w >> 1, wc = w & 1;        // wave grid 2 x 2
  const int l31 = lane & 31, kh = lane >> 5;

  // staging chunk geometry: 4 x 16B per operand per K-tile per thread
  int srcOff[4], ldsOff[4];
#pragma unroll
  for (int cpy = 0; cpy < 4; ++cpy) {
    const int c = cpy * 256 + t;            // [0,1024)
    const int row = c >> 3, s = c & 7;
    srcOff[cpy] = row * DIM + s * 16;
    ldsOff[cpy] = row * LSTR + ((s ^ (row & 7)) << 4);
  }
  const signed char* bBase = mq + (size_t)j0 * DIM;

  int mn_[2];                               // col-norms for this thread's cols
#pragma unroll
  for (int ni = 0; ni < 2; ++ni) mn_[ni] = mni[j0 + wc * 64 + ni * 32 + l31];

  const int tcount = (agroup == 0) ? 13 : 12;
#pragma unroll 1
  for (int k7 = 0; k7 < tcount; ++k7) {
    const int tile = agroup + 4 * k7;       // residue classes cover [0,49)
    const int r0 = tile * BMS;
    const signed char* aBase = xq + (size_t)r0 * DIM;

    i32x16 acc[2][2];
#pragma unroll
    for (int mi = 0; mi < 2; ++mi)
#pragma unroll
      for (int ni = 0; ni < 2; ++ni)
#pragma unroll
        for (int r = 0; r < 16; ++r) acc[mi][ni][r] = 0;

    i32x4 ra[4], rb[4];
    // prologue: K-tile 0 -> buf0
#pragma unroll
    for (int cpy = 0; cpy < 4; ++cpy) {
      ra[cpy] = *(const i32x4*)(aBase + srcOff[cpy]);
      rb[cpy] = *(const i32x4*)(bBase + srcOff[cpy]);
    }
#pragma unroll
    for (int cpy = 0; cpy < 4; ++cpy) {
      *(i32x4*)(S + ldsOff[cpy]) = ra[cpy];
      *(i32x4*)(S + 40960 + ldsOff[cpy]) = rb[cpy];
    }
    asm volatile("s_waitcnt lgkmcnt(0)" ::: "memory");
    __builtin_amdgcn_s_barrier();

#pragma unroll 1
    for (int kt = 0; kt < 8; ++kt) {
      const int cb = (kt & 1) * 20480;
      const signed char* Ab = S + cb;
      const signed char* Bb = S + 40960 + cb;
      if (kt < 7) {                         // issue next-tile loads early
        const int kk = (kt + 1) * 128;
#pragma unroll
        for (int cpy = 0; cpy < 4; ++cpy) {
          ra[cpy] = *(const i32x4*)(aBase + srcOff[cpy] + kk);
          rb[cpy] = *(const i32x4*)(bBase + srcOff[cpy] + kk);
        }
      }
      __builtin_amdgcn_s_setprio(1);
#pragma unroll
      for (int ks = 0; ks < 4; ++ks) {
        const int sr = 2 * ks + kh;
        i32x4 a[2], b[2];
#pragma unroll
        for (int mi = 0; mi < 2; ++mi) {
          const int r = wr * 64 + mi * 32 + l31;
          a[mi] = *(const i32x4*)(Ab + r * LSTR + ((sr ^ (r & 7)) << 4));
        }
#pragma unroll
        for (int ni = 0; ni < 2; ++ni) {
          const int r = wc * 64 + ni * 32 + l31;
          b[ni] = *(const i32x4*)(Bb + r * LSTR + ((sr ^ (r & 7)) << 4));
        }
#pragma unroll
        for (int mi = 0; mi < 2; ++mi)
#pragma unroll
          for (int ni = 0; ni < 2; ++ni)
            acc[mi][ni] = __builtin_amdgcn_mfma_i32_32x32x32_i8(a[mi], b[ni], acc[mi][ni], 0, 0, 0);
      }
      __builtin_amdgcn_s_setprio(0);
      if (kt < 7) {                         // write next tile to other buf
        const int nb = ((kt + 1) & 1) * 20480;
#pragma unroll
        for (int cpy = 0; cpy < 4; ++cpy) {
          *(i32x4*)(S + nb + ldsOff[cpy]) = ra[cpy];
          *(i32x4*)(S + 40960 + nb + ldsOff[cpy]) = rb[cpy];
        }
      }
      asm volatile("s_waitcnt lgkmcnt(0)" ::: "memory");
      __builtin_amdgcn_s_barrier();         // buf[kt+1] visible / reads done
    }

    // ---- epilogue: int keys -> swizzled Kbuf; per-(row,half) top-6 ----
#pragma unroll
    for (int mi = 0; mi < 2; ++mi)
#pragma unroll
      for (int ni = 0; ni < 2; ++ni) {
        const int col = wc * 64 + ni * 32 + l31;
        const int mn = mn_[ni];
#pragma unroll
        for (int r = 0; r < 16; ++r) {
          const int row = wr * 64 + mi * 32 + 4 * kh + (r & 3) + 8 * (r >> 2);
          Kbuf[row * 128 + kswz(row, col)] = mn - 2 * acc[mi][ni][r];
        }
      }
    __syncthreads();
    {
      const int row = t >> 1, half = t & 1;
      unsigned tk[TOPC];
#pragma unroll
      for (int s = 0; s < TOPC; ++s) tk[s] = 0xFFFFFFFFu;
#pragma unroll
      for (int q = 0; q < 16; ++q) {
        const int cl = half * 64 + q * 4;
        const i32x4 v = *(const i32x4*)(Kbuf + row * 128 + kswz(row, cl));
#pragma unroll
        for (int e = 0; e < 4; ++e) {
          // pack: 18-bit biased key | 14-bit global j (monotone in key)
          const unsigned p = (((unsigned)(v[e] + (1 << 25)) >> 11) << 14)
                             | (unsigned)(j0 + cl + e);
          if (p < tk[0]) {                  // replace max, bubble (sorted desc)
            tk[0] = p;
#pragma unroll
            for (int s = 0; s < TOPC - 1; ++s) {
              const unsigned hi = tk[s] > tk[s + 1] ? tk[s] : tk[s + 1];
              const unsigned lo = tk[s] > tk[s + 1] ? tk[s + 1] : tk[s];
              tk[s] = hi; tk[s + 1] = lo;
            }
          }
        }
      }
      const size_t base = (size_t)(r0 + row) * NCAND + (size_t)(pglob * 2 + half) * TOPC;
#pragma unroll
      for (int s = 0; s < TOPC; ++s) cand[base + s] = tk[s];
    }
    __syncthreads();                        // scans done before next prologue
  }
}

// ---- merge 1536 candidates -> top-16 -> fp64 rerank -> top-9 (R10-proven) ----
__global__ void k_rerank(const float* __restrict__ xf, const float* __restrict__ mb,
                         const unsigned int* __restrict__ cand,
                         int* __restrict__ idx9, double* __restrict__ dsv) {
  const int n = blockIdx.x, t = threadIdx.x;
  __shared__ float    xs[DIM];
  __shared__ unsigned cs[NCAND];
  __shared__ unsigned sel[TRR];
  __shared__ double dpart[256];
  __shared__ double d2s[TRR];
  __shared__ double dist_s[TRR];
  __shared__ int    rank_s[TRR];

  const float* xrow = xf + (size_t)n * DIM;
  for (int c = t; c < DIM; c += 256) xs[c] = xrow[c];
  const size_t cb = (size_t)n * NCAND;
  for (int s = t; s < NCAND; s += 256) cs[s] = cand[cb + s];
  __syncthreads();

  if (t < 64) {  // wave 0: 64 lanes x 24 items, 16 extract-min rounds
    unsigned ck[24];
#pragma unroll
    for (int s = 0; s < 24; ++s) ck[s] = cs[t + 64 * s];
    for (int it = 0; it < TRR; ++it) {
      unsigned best = ck[0];
#pragma unroll
      for (int s = 1; s < 24; ++s) best = best < ck[s] ? best : ck[s];
#pragma unroll
      for (int off = 32; off >= 1; off >>= 1) {
        const unsigned o = (unsigned)__shfl_xor((int)best, off);
        best = best < o ? best : o;
      }
      if (t == 0) sel[it] = best;
#pragma unroll
      for (int s = 0; s < 24; ++s) if (ck[s] == best) ck[s] = 0xFFFFFFFFu;
    }
  }
  __syncthreads();
  {
    const int s = t >> 4, l16 = t & 15;
    const int j = (int)(sel[s] & 16383u);
    const float* mrow = mb + (size_t)j * DIM;
    double a = 0.0;
    for (int i = 0; i < 64; ++i) {
      const int c = l16 + (i << 4);
      const double d = (double)xs[c] - (double)mrow[c];
      a += d * d;
    }
    dpart[t] = a;
  }
  __syncthreads();
  if (t < TRR) {
    double v = 0.0;
    for (int i = 0; i < 16; ++i) v += dpart[t * 16 + i];
    d2s[t] = v;
    dist_s[t] = sqrt(v < 1e-12 ? 1e-12 : v);
  }
  __syncthreads();
  if (t < TRR) {
    const double v = d2s[t]; const int id = (int)(sel[t] & 16383u);
    int r = 0;
    for (int u = 0; u < TRR; ++u) {
      const double vu = d2s[u];
      const int idu = (int)(sel[u] & 16383u);
      if (vu < v || (vu == v && idu < id)) ++r;
    }
    rank_s[t] = r;
    if (r < KNN) idx9[n * KNN + r] = id;
  }
  __syncthreads();
  if (t == 0) {
    double sum = 0.0;
    for (int u = 0; u < TRR; ++u) if (rank_s[u] < KNN) sum += dist_s[u];
    dsv[n] = sum * (1.0 / KNN);
  }
}

// ---- global mean/std of per-row mean distance (R10-proven) ----
__global__ void k_dsstats(const double* __restrict__ dsv, double* __restrict__ stats) {
  __shared__ double red[1024];
  const int t = threadIdx.x;
  double s = 0.0;
  for (int i = t; i < N_ROWS; i += 1024) s += dsv[i];
  red[t] = s; __syncthreads();
  for (int o = 512; o >= 1; o >>= 1) { if (t < o) red[t] += red[t + o]; __syncthreads(); }
  const double mean = red[0] / (double)N_ROWS;
  __syncthreads();
  double v = 0.0;
  for (int i = t; i < N_ROWS; i += 1024) { const double d = dsv[i] - mean; v += d * d; }
  red[t] = v; __syncthreads();
  for (int o = 512; o >= 1; o >>= 1) { if (t < o) red[t] += red[t + o]; __syncthreads(); }
  if (t == 0) {
    const double fullstd = sqrt(red[0] * (double)DIM / ((double)N_ROWS * DIM - 1.0));
    stats[0] = mean;
    stats[1] = fullstd + 1e-8;
  }
}

// ---- influence, row-norm, sigmoid noise, fused NCHW write + maps (R10) ----
__global__ void k_final(const float* __restrict__ xf, const float* __restrict__ mb,
                        const float* __restrict__ iw, const float* __restrict__ dwp,
                        const float* __restrict__ eps, const int* __restrict__ idx9,
                        const double* __restrict__ dsv, const double* __restrict__ stats,
                        float* __restrict__ out) {
  const int n = blockIdx.x, t = threadIdx.x;
  __shared__ float xs[DIM];
  __shared__ int js[KNN];
  __shared__ float rs1[4], rs2[4];
  const float* xrow = xf + (size_t)n * DIM;
  for (int c = t; c < DIM; c += 256) xs[c] = xrow[c];
  if (t < KNN) js[t] = idx9[n * KNN + t];
  __syncthreads();

  float infl[4];
  float s1 = 0.f, s2 = 0.f;
#pragma unroll
  for (int q = 0; q < 4; ++q) {
    const int c = t + q * 256;
    const float x = xs[c];
    float a = 0.f;
#pragma unroll
    for (int k = 0; k < KNN; ++k) a += fabsf(x - mb[(size_t)js[k] * DIM + c]);
    const float v = a * (1.0f / KNN) * iw[c];
    infl[q] = v; s1 += v; s2 += v * v;
  }
#pragma unroll
  for (int o = 32; o >= 1; o >>= 1) { s1 += __shfl_down(s1, o); s2 += __shfl_down(s2, o); }
  if ((t & 63) == 0) { rs1[t >> 6] = s1; rs2[t >> 6] = s2; }
  __syncthreads();
  const float sum = rs1[0] + rs1[1] + rs1[2] + rs1[3];
  const float sq  = rs2[0] + rs2[1] + rs2[2] + rs2[3];
  const float mean = sum * (1.0f / DIM);
  float var = (sq - (float)DIM * mean * mean) * (1.0f / (DIM - 1));
  var = fmaxf(var, 0.f);
  const float inv = 1.0f / (sqrtf(var) + 1e-8f);
  const float dn = (float)(((double)dsv[n] - stats[0]) / stats[1]);
  const float zb = dwp[0] * dn;

  const int b = n / 784, hw = n % 784;
  float* op = out + (size_t)b * (1024 * 784) + hw;
  const float* ep = eps + (size_t)n * DIM;
  float si = 0.f, sn = 0.f;
#pragma unroll
  for (int q = 0; q < 4; ++q) {
    const int c = t + q * 256;
    const float v = infl[q];
    const float z = (v - mean) * inv + zb;
    const float ns = 0.01f + 0.49f / (1.0f + expf(-z));
    op[(size_t)c * 784] = xs[c] + ep[c] * ns;   // L2 absorbs the n-adjacent scatter
    si += v; sn += ns;
  }
  __syncthreads();  // rs1/rs2 reads above complete before reuse
#pragma unroll
  for (int o = 32; o >= 1; o >>= 1) { si += __shfl_down(si, o); sn += __shfl_down(sn, o); }
  if ((t & 63) == 0) { rs1[t >> 6] = si; rs2[t >> 6] = sn; }
  __syncthreads();
  if (t == 0) {
    out[6422528 + n]        = (rs1[0] + rs1[1] + rs1[2] + rs1[3]) * (1.0f / DIM);
    out[6422528 + 6272 + n] = (rs2[0] + rs2[1] + rs2[2] + rs2[3]) * (1.0f / DIM);
  }
}

extern "C" void kernel_launch(void* const* d_in, const int* in_sizes, int n_in,
                              void* d_out, int out_size, void* d_ws, size_t ws_size,
                              hipStream_t stream) {
  (void)in_sizes; (void)n_in; (void)out_size; (void)ws_size;
  const float* feat = (const float*)d_in[0];
  const float* mb   = (const float*)d_in[1];
  const float* iw   = (const float*)d_in[2];
  const float* dw   = (const float*)d_in[3];
  const float* eps  = (const float*)d_in[4];
  float* out = (float*)d_out;

  char* p = (char*)d_ws;
  float* xf = (float*)p;                     p += (size_t)N_ROWS * DIM * 4;
  signed char* xq = (signed char*)p;         p += (size_t)N_ROWS * DIM;
  signed char* mq = (signed char*)p;         p += (size_t)M_ROWS * DIM;
  int* mni = (int*)p;                        p += (size_t)M_ROWS * 4;
  unsigned int* cand = (unsigned int*)p;     p += (size_t)N_ROWS * NCAND * 4;
  int* idx9 = (int*)p;                       p += (size_t)N_ROWS * KNN * 4;
  p = (char*)(((uintptr_t)p + 255) & ~(uintptr_t)255);
  double* dsv = (double*)p;                  p += (size_t)N_ROWS * 8;
  double* stats = (double*)p;                p += 64;
  // total ~88 MB of d_ws

  k_prep_x<<<6272, 256, 0, stream>>>(feat, xf, xq);
  k_prep_m<<<M_ROWS, 256, 0, stream>>>(mb, mq, mni);
  k_score<<<512, 256, 0, stream>>>(xq, mq, mni, cand);
  k_rerank<<<N_ROWS, 256, 0, stream>>>(xf, mb, cand, idx9, dsv);
  k_dsstats<<<1, 1024, 0, stream>>>(dsv, stats);
  k_final<<<N_ROWS, 256, 0, stream>>>(xf, mb, iw, dw, eps, idx9, dsv, stats, out);
}